// Round 4
// baseline (381.044 us; speedup 1.0000x reference)
//
#include <hip/hip_runtime.h>

// CenterShift: out[n,o] = x[n] * (celu(celu((pos_j-pos_i)@w11+b11)@w12+b12) @ w13 + b13)[o]
// N = 2097152, dims 3 -> 16 -> 64 -> 64, fp32 in/out.
//
// Round 4 = r2 skeleton + r3's proven pieces, minus r3's regressions:
//  - one 64-point tile per wave, 8192 blocks, per-wave LDS, no syncthreads
//  - layer 2 AND layer 3 via mfma_f32_16x16x32_f16 (swapped operands D[o,p];
//    layouts correctness-proven in r2/r3)
//  - compact XOR-swizzled h2 tile (8 KB/wave, 32 KB/block -> 5 blocks/CU LDS-wise)
//  - DIRECT global stores (r2 pattern: per (t,u) the 4 lane-groups cover a
//    contiguous 64B quarter-row per point -> full sectors, 1x write amp).
//    NO LDS out-staging (r3's serializing mistake).

typedef __attribute__((ext_vector_type(8))) _Float16 f16x8;
typedef __attribute__((ext_vector_type(4))) float f32x4;

__device__ __forceinline__ float celu1(float a) {
    return a > 0.0f ? a : __expf(a) - 1.0f;
}

__global__ __launch_bounds__(256, 4) void centershift_kernel(
    const float* __restrict__ x,
    const float* __restrict__ pos_i,
    const float* __restrict__ pos_j,
    const float* __restrict__ w11, const float* __restrict__ b11,
    const float* __restrict__ w12, const float* __restrict__ b12,
    const float* __restrict__ w13, const float* __restrict__ b13,
    float* __restrict__ out, int n)
{
    __shared__ __align__(16) _Float16 h2s[4][64 * 64];  // 8 KB/wave, swizzled

    const int lane = threadIdx.x & 63;
    const int wid  = threadIdx.x >> 6;
    const int g    = lane >> 4;    // 16-lane group 0..3
    const int r16  = lane & 15;
    const int swz  = (r16 & 7) << 4;

    const int tb = (blockIdx.x * 4 + wid) * 64;   // 64 points per wave
    if (tb >= n) return;

    // ---- fragments ----
    // layer-3 A = w13^T: A[row=o_local=r16][k=kh*32+g*8+j]
    f16x8 a3[4][2];
#pragma unroll
    for (int u = 0; u < 4; ++u)
#pragma unroll
        for (int kh = 0; kh < 2; ++kh) {
            f16x8 v;
#pragma unroll
            for (int j = 0; j < 8; ++j)
                v[j] = (_Float16)w13[(kh * 32 + g * 8 + j) * 64 + u * 16 + r16];
            a3[u][kh] = v;
        }
    // layer-2 A = w12^T, K zero-padded 16->32
    f16x8 a2[4];
#pragma unroll
    for (int u2 = 0; u2 < 4; ++u2) {
        f16x8 v;
#pragma unroll
        for (int j = 0; j < 8; ++j) {
            const int k = g * 8 + j;
            v[j] = (k < 16) ? (_Float16)w12[k * 64 + u2 * 16 + r16] : (_Float16)0.0f;
        }
        a2[u2] = v;
    }
    // biases in C/D layout: lane holds rows o = u*16 + g*4 + rr
    float b2v[4][4], b3v[4][4];
#pragma unroll
    for (int u = 0; u < 4; ++u)
#pragma unroll
        for (int rr = 0; rr < 4; ++rr) {
            b2v[u][rr] = b12[u * 16 + g * 4 + rr];
            b3v[u][rr] = b13[u * 16 + g * 4 + rr];
        }

    char* h2b = (char*)&h2s[wid][0];

    // ---- layers 1+2: four 16-point column tiles -> swizzled LDS ----
#pragma unroll
    for (int t = 0; t < 4; ++t) {
        const int pt = t * 16 + r16;
        const int q  = tb + pt;
        const float3 pi = *reinterpret_cast<const float3*>(pos_i + 3 * (size_t)q);
        const float3 pj = *reinterpret_cast<const float3*>(pos_j + 3 * (size_t)q);
        const float p0 = pj.x - pi.x, p1 = pj.y - pi.y, p2 = pj.z - pi.z;

        // h1 channels [ch0, ch0+8) of point q; B[k=g*8+j][col=r16]
        const int ch0 = (g & 1) * 8;
        f16x8 b2f;
#pragma unroll
        for (int j = 0; j < 8; ++j) {
            const int c = ch0 + j;
            float a = b11[c];
            a = fmaf(p0, w11[c], a);
            a = fmaf(p1, w11[16 + c], a);
            a = fmaf(p2, w11[32 + c], a);
            a = celu1(a);
            b2f[j] = (g < 2) ? (_Float16)a : (_Float16)0.0f;
        }
#pragma unroll
        for (int u2 = 0; u2 < 4; ++u2) {
            f32x4 acc = { b2v[u2][0], b2v[u2][1], b2v[u2][2], b2v[u2][3] };
            acc = __builtin_amdgcn_mfma_f32_16x16x32_f16(a2[u2], b2f, acc, 0, 0, 0);
            union { _Float16 h[4]; unsigned long long v; } pk;
            pk.h[0] = (_Float16)celu1(acc[0]);
            pk.h[1] = (_Float16)celu1(acc[1]);
            pk.h[2] = (_Float16)celu1(acc[2]);
            pk.h[3] = (_Float16)celu1(acc[3]);
            // h2[pt][ch = u2*16 + g*4 + 0..3], byte = pt*128 + ch*2, swizzled
            const int byteoff = pt * 128 + u2 * 32 + g * 8;
            *reinterpret_cast<unsigned long long*>(h2b + (byteoff ^ swz)) = pk.v;
        }
    }

    // ---- layer 3: MFMA + direct stores ----
#pragma unroll
    for (int t2 = 0; t2 < 4; ++t2) {
        const int pt = t2 * 16 + r16;
        const f16x8 bb0 = *reinterpret_cast<const f16x8*>(h2b + ((pt * 128 +      g * 16) ^ swz));
        const f16x8 bb1 = *reinterpret_cast<const f16x8*>(h2b + ((pt * 128 + 64 + g * 16) ^ swz));
        const float xvt = x[tb + pt];
        float* optr = out + (size_t)(tb + pt) * 64;
#pragma unroll
        for (int u = 0; u < 4; ++u) {
            f32x4 acc = { b3v[u][0], b3v[u][1], b3v[u][2], b3v[u][3] };
            acc = __builtin_amdgcn_mfma_f32_16x16x32_f16(a3[u][0], bb0, acc, 0, 0, 0);
            acc = __builtin_amdgcn_mfma_f32_16x16x32_f16(a3[u][1], bb1, acc, 0, 0, 0);
            // lane holds out channels o = u*16 + g*4 + {0..3} of point tb+pt
            float4 o4 = { acc[0] * xvt, acc[1] * xvt, acc[2] * xvt, acc[3] * xvt };
            *reinterpret_cast<float4*>(optr + u * 16 + g * 4) = o4;
        }
    }
}

extern "C" void kernel_launch(void* const* d_in, const int* in_sizes, int n_in,
                              void* d_out, int out_size, void* d_ws, size_t ws_size,
                              hipStream_t stream) {
    const float* x     = (const float*)d_in[0];
    const float* pos_i = (const float*)d_in[1];
    const float* pos_j = (const float*)d_in[2];
    const float* w11   = (const float*)d_in[3];
    const float* b11   = (const float*)d_in[4];
    const float* w12   = (const float*)d_in[5];
    const float* b12   = (const float*)d_in[6];
    const float* w13   = (const float*)d_in[7];
    const float* b13   = (const float*)d_in[8];
    float* out = (float*)d_out;

    const int n = in_sizes[0];                 // N (x is [N,1])
    const int blocks = (n + 255) / 256;        // 4 waves/block, 64 points/wave
    centershift_kernel<<<blocks, 256, 0, stream>>>(
        x, pos_i, pos_j, w11, b11, w12, b12, w13, b13, out, n);
}

// Round 5
// 267.888 us; speedup vs baseline: 1.4224x; 1.4224x over previous
//
#include <hip/hip_runtime.h>

// CenterShift: out[n,o] = x[n] * (celu(celu((pos_j-pos_i)@w11+b11)@w12+b12) @ w13 + b13)[o]
// N = 2097152, dims 3 -> 16 -> 64 -> 64, fp32 in/out.
//
// Round 5 = round 4 structure with the spill bug fixed:
//  - __launch_bounds__(256) ONLY. r4's (256,4) forced VGPR=64 < the ~80-reg
//    persistent fragment state -> scratch spills (FETCH +150MB, WRITE +360MB,
//    390us). Let the allocator float (~130 VGPR, 3 waves/SIMD).
//  - one 64-point tile per wave, per-wave LDS, no __syncthreads
//  - layers 2+3 via mfma_f32_16x16x32_f16 (swapped operands D[o,p]; layout
//    proven r2-r4), layer-2 K zero-padded 16->32
//  - compact XOR-swizzled h2 tile (8 KB/wave, 32 KB/block)
//  - direct full-sector stores (r2 pattern: 4 lane-groups cover a contiguous
//    64B quarter-row per point)
//  - x loaded coalesced once, broadcast via __shfl (r2 pattern)

typedef __attribute__((ext_vector_type(8))) _Float16 f16x8;
typedef __attribute__((ext_vector_type(4))) float f32x4;

__device__ __forceinline__ float celu1(float a) {
    return a > 0.0f ? a : __expf(a) - 1.0f;
}

__global__ __launch_bounds__(256) void centershift_kernel(
    const float* __restrict__ x,
    const float* __restrict__ pos_i,
    const float* __restrict__ pos_j,
    const float* __restrict__ w11, const float* __restrict__ b11,
    const float* __restrict__ w12, const float* __restrict__ b12,
    const float* __restrict__ w13, const float* __restrict__ b13,
    float* __restrict__ out, int n)
{
    __shared__ __align__(16) _Float16 h2s[4][64 * 64];  // 8 KB/wave, swizzled

    const int lane = threadIdx.x & 63;
    const int wid  = threadIdx.x >> 6;
    const int g    = lane >> 4;    // 16-lane group 0..3
    const int r16  = lane & 15;
    const int swz  = (r16 & 7) << 4;

    const int tb = (blockIdx.x * 4 + wid) * 64;   // 64 points per wave
    if (tb >= n) return;

    // ---- fragments (persistent; ~80 VGPR -- needs unconstrained allocator) ----
    // layer-3 A = w13^T: A[row=o_local=r16][k=kh*32+g*8+j]
    f16x8 a3[4][2];
#pragma unroll
    for (int u = 0; u < 4; ++u)
#pragma unroll
        for (int kh = 0; kh < 2; ++kh) {
            f16x8 v;
#pragma unroll
            for (int j = 0; j < 8; ++j)
                v[j] = (_Float16)w13[(kh * 32 + g * 8 + j) * 64 + u * 16 + r16];
            a3[u][kh] = v;
        }
    // layer-2 A = w12^T, K zero-padded 16->32
    f16x8 a2[4];
#pragma unroll
    for (int u2 = 0; u2 < 4; ++u2) {
        f16x8 v;
#pragma unroll
        for (int j = 0; j < 8; ++j) {
            const int k = g * 8 + j;
            v[j] = (k < 16) ? (_Float16)w12[k * 64 + u2 * 16 + r16] : (_Float16)0.0f;
        }
        a2[u2] = v;
    }
    // biases in C/D layout: lane holds rows o = u*16 + g*4 + rr
    float b2v[4][4], b3v[4][4];
#pragma unroll
    for (int u = 0; u < 4; ++u)
#pragma unroll
        for (int rr = 0; rr < 4; ++rr) {
            b2v[u][rr] = b12[u * 16 + g * 4 + rr];
            b3v[u][rr] = b13[u * 16 + g * 4 + rr];
        }

    char* h2b = (char*)&h2s[wid][0];

    // coalesced x load, broadcast later via shfl
    const float xv = x[tb + lane];

    // ---- layers 1+2: four 16-point column tiles -> swizzled LDS ----
#pragma unroll
    for (int t = 0; t < 4; ++t) {
        const int pt = t * 16 + r16;
        const int q  = tb + pt;
        const float3 pi = *reinterpret_cast<const float3*>(pos_i + 3 * (size_t)q);
        const float3 pj = *reinterpret_cast<const float3*>(pos_j + 3 * (size_t)q);
        const float p0 = pj.x - pi.x, p1 = pj.y - pi.y, p2 = pj.z - pi.z;

        // h1 channels [ch0, ch0+8) of point q; B[k=g*8+j][col=r16]
        const int ch0 = (g & 1) * 8;
        f16x8 b2f;
#pragma unroll
        for (int j = 0; j < 8; ++j) {
            const int c = ch0 + j;
            float a = b11[c];
            a = fmaf(p0, w11[c], a);
            a = fmaf(p1, w11[16 + c], a);
            a = fmaf(p2, w11[32 + c], a);
            a = celu1(a);
            b2f[j] = (g < 2) ? (_Float16)a : (_Float16)0.0f;
        }
#pragma unroll
        for (int u2 = 0; u2 < 4; ++u2) {
            f32x4 acc = { b2v[u2][0], b2v[u2][1], b2v[u2][2], b2v[u2][3] };
            acc = __builtin_amdgcn_mfma_f32_16x16x32_f16(a2[u2], b2f, acc, 0, 0, 0);
            union { _Float16 h[4]; unsigned long long v; } pk;
            pk.h[0] = (_Float16)celu1(acc[0]);
            pk.h[1] = (_Float16)celu1(acc[1]);
            pk.h[2] = (_Float16)celu1(acc[2]);
            pk.h[3] = (_Float16)celu1(acc[3]);
            // h2[pt][ch = u2*16 + g*4 + 0..3], byte = pt*128 + ch*2, swizzled
            const int byteoff = pt * 128 + u2 * 32 + g * 8;
            *reinterpret_cast<unsigned long long*>(h2b + (byteoff ^ swz)) = pk.v;
        }
    }

    // ---- layer 3: MFMA + direct full-sector stores ----
#pragma unroll
    for (int t2 = 0; t2 < 4; ++t2) {
        const int pt = t2 * 16 + r16;
        const f16x8 bb0 = *reinterpret_cast<const f16x8*>(h2b + ((pt * 128 +      g * 16) ^ swz));
        const f16x8 bb1 = *reinterpret_cast<const f16x8*>(h2b + ((pt * 128 + 64 + g * 16) ^ swz));
        const float xvt = __shfl(xv, pt);
        float* optr = out + (size_t)(tb + pt) * 64;
#pragma unroll
        for (int u = 0; u < 4; ++u) {
            f32x4 acc = { b3v[u][0], b3v[u][1], b3v[u][2], b3v[u][3] };
            acc = __builtin_amdgcn_mfma_f32_16x16x32_f16(a3[u][0], bb0, acc, 0, 0, 0);
            acc = __builtin_amdgcn_mfma_f32_16x16x32_f16(a3[u][1], bb1, acc, 0, 0, 0);
            // lane holds out channels o = u*16 + g*4 + {0..3} of point tb+pt
            float4 o4 = { acc[0] * xvt, acc[1] * xvt, acc[2] * xvt, acc[3] * xvt };
            *reinterpret_cast<float4*>(optr + u * 16 + g * 4) = o4;
        }
    }
}

extern "C" void kernel_launch(void* const* d_in, const int* in_sizes, int n_in,
                              void* d_out, int out_size, void* d_ws, size_t ws_size,
                              hipStream_t stream) {
    const float* x     = (const float*)d_in[0];
    const float* pos_i = (const float*)d_in[1];
    const float* pos_j = (const float*)d_in[2];
    const float* w11   = (const float*)d_in[3];
    const float* b11   = (const float*)d_in[4];
    const float* w12   = (const float*)d_in[5];
    const float* b12   = (const float*)d_in[6];
    const float* w13   = (const float*)d_in[7];
    const float* b13   = (const float*)d_in[8];
    float* out = (float*)d_out;

    const int n = in_sizes[0];                 // N (x is [N,1])
    const int blocks = (n + 255) / 256;        // 4 waves/block, 64 points/wave
    centershift_kernel<<<blocks, 256, 0, stream>>>(
        x, pos_i, pos_j, w11, b11, w12, b12, w13, b13, out, n);
}